// Round 5
// baseline (387.993 us; speedup 1.0000x reference)
//
#include <hip/hip_runtime.h>
#include <hip/hip_bf16.h>

// ---------------------------------------------------------------------------
// CapsNet forward, fp32. B=512.
// convs: banded blocks (band of 8 pool-rows), padded input in LDS, relu+pool.
// routing1/2: register-resident; reductions via recursive-halving
//             reduce-scatter + LDS broadcast-back (not full butterflies).
// ---------------------------------------------------------------------------

__device__ __forceinline__ void lds_fence() {
    asm volatile("s_waitcnt lgkmcnt(0)" ::: "memory");
}

// Reduce-scatter sum of NV values over 64 lanes. t[] is destroyed.
// Returns full sum for index j = lane & (NV-1).
template<int NV>
__device__ __forceinline__ float halve_sum(float* t, int lane) {
#pragma unroll
    for (int m = NV >> 1; m >= 1; m >>= 1) {
        bool hi = (lane & m) != 0;
#pragma unroll
        for (int j = 0; j < m; ++j) {
            float keep = hi ? t[j + m] : t[j];
            float send = hi ? t[j] : t[j + m];
            t[j] = keep + __shfl_xor(send, m, 64);
        }
    }
    float v = t[0];
#pragma unroll
    for (int m = NV; m < 64; m <<= 1) v += __shfl_xor(v, m, 64);
    return v;
}

template<int NV>
__device__ __forceinline__ float halve_max(float* t, int lane) {
#pragma unroll
    for (int m = NV >> 1; m >= 1; m >>= 1) {
        bool hi = (lane & m) != 0;
#pragma unroll
        for (int j = 0; j < m; ++j) {
            float keep = hi ? t[j + m] : t[j];
            float send = hi ? t[j] : t[j + m];
            t[j] = fmaxf(keep, __shfl_xor(send, m, 64));
        }
    }
    float v = t[0];
#pragma unroll
    for (int m = NV; m < 64; m <<= 1) v = fmaxf(v, __shfl_xor(v, m, 64));
    return v;
}

// Banded fused conv3x3(SAME) + ReLU + maxpool2. Grid = (B, HOUT/BANDH).
template<int CIN, int COUT, int HIN, int NO, int BANDH>
__global__ __launch_bounds__(256)
void conv_relu_pool(const float* __restrict__ in, const float* __restrict__ w,
                    const float* __restrict__ bias, float* __restrict__ out)
{
    constexpr int HOUT = HIN / 2;
    constexpr int ROWS = 2 * BANDH + 2;
    constexpr int PC = (HIN + 2 + 3) & ~3;
    constexpr int NS = HIN / 8;
    constexpr int XWORDS = CIN * ROWS * PC;
    constexpr int WWORDS = CIN * 9 * COUT;
    static_assert((COUT / NO) * BANDH * NS == 256, "one task per thread");

    __shared__ float xin[CIN][ROWS][PC];
    __shared__ float wt[WWORDS];                // [c][k][o]
    __shared__ float bl[COUT];

    const int tid  = threadIdx.x;
    const int b    = blockIdx.x;
    const int band = blockIdx.y;
    const int y0   = 2 * (band * BANDH) - 1;    // global y of LDS row 0

    for (int i = tid; i < XWORDS; i += 256) ((float*)xin)[i] = 0.f;
    for (int i = tid; i < WWORDS; i += 256) {
        int o = i % COUT, k = (i / COUT) % 9, c = i / (COUT * 9);
        wt[i] = w[(o * CIN + c) * 9 + k];
    }
    if (tid < COUT) bl[tid] = bias[tid];
    __syncthreads();

    const float4* gin = (const float4*)(in + (size_t)b * CIN * HIN * HIN);
    constexpr int CHUNKS = CIN * ROWS * (HIN / 4);
    for (int i = tid; i < CHUNKS; i += 256) {
        int ch = i % (HIN / 4);
        int ly = (i / (HIN / 4)) % ROWS;
        int c  = i / ((HIN / 4) * ROWS);
        int y  = y0 + ly;
        if (y >= 0 && y < HIN) {
            float4 v = gin[(c * HIN + y) * (HIN / 4) + ch];
            float* dst = &xin[c][ly][1 + ch * 4];
            dst[0] = v.x; dst[1] = v.y; dst[2] = v.z; dst[3] = v.w;
        }
    }
    __syncthreads();

    const int s  = tid % NS;
    const int py = (tid / NS) % BANDH;
    const int o0 = (tid / (NS * BANDH)) * NO;
    const int X0 = s * 8;

    float acc[NO][2][8];
#pragma unroll
    for (int n = 0; n < NO; ++n)
#pragma unroll
        for (int q = 0; q < 2; ++q)
#pragma unroll
            for (int j = 0; j < 8; ++j) acc[n][q][j] = 0.f;

    for (int c = 0; c < CIN; ++c) {
        float rows[4][12];
#pragma unroll
        for (int rr = 0; rr < 4; ++rr) {
            const float4* src = (const float4*)&xin[c][2 * py + rr][X0];
#pragma unroll
            for (int j = 0; j < 3; ++j) {
                float4 v = src[j];
                rows[rr][j * 4 + 0] = v.x; rows[rr][j * 4 + 1] = v.y;
                rows[rr][j * 4 + 2] = v.z; rows[rr][j * 4 + 3] = v.w;
            }
        }
        const float* wc = wt + c * 9 * COUT;
#pragma unroll
        for (int ky = 0; ky < 3; ++ky) {
#pragma unroll
            for (int n = 0; n < NO; ++n) {
                const float w0 = wc[(ky * 3 + 0) * COUT + o0 + n];
                const float w1 = wc[(ky * 3 + 1) * COUT + o0 + n];
                const float w2 = wc[(ky * 3 + 2) * COUT + o0 + n];
#pragma unroll
                for (int j = 0; j < 8; ++j) {
                    acc[n][0][j] = fmaf(rows[ky][j],     w0, acc[n][0][j]);
                    acc[n][0][j] = fmaf(rows[ky][j + 1], w1, acc[n][0][j]);
                    acc[n][0][j] = fmaf(rows[ky][j + 2], w2, acc[n][0][j]);
                    acc[n][1][j] = fmaf(rows[ky + 1][j],     w0, acc[n][1][j]);
                    acc[n][1][j] = fmaf(rows[ky + 1][j + 1], w1, acc[n][1][j]);
                    acc[n][1][j] = fmaf(rows[ky + 1][j + 2], w2, acc[n][1][j]);
                }
            }
        }
    }
#pragma unroll
    for (int n = 0; n < NO; ++n) {
        const float bv = bl[o0 + n];
        float4 ov;
        float* p = (float*)&ov;
#pragma unroll
        for (int j = 0; j < 4; ++j) {
            float m = fmaxf(fmaxf(acc[n][0][2 * j], acc[n][0][2 * j + 1]),
                            fmaxf(acc[n][1][2 * j], acc[n][1][2 * j + 1]));
            p[j] = fmaxf(m + bv, 0.f);
        }
        float* po = out + (((size_t)b * COUT + o0 + n) * HOUT + band * BANDH + py) * HOUT + s * 4;
        *(float4*)po = ov;
    }
}

// W[n][r][c][o] -> Wt[n][c][r][o]  (n=32, r=64, c=32, o=8), float4 granules.
__global__ __launch_bounds__(256)
void transpose_w1(const float* __restrict__ W, float* __restrict__ Wt)
{
    int idx = blockIdx.x * 256 + threadIdx.x;
    if (idx >= 32 * 32 * 64 * 2) return;
    int half = idx & 1;
    int r    = (idx >> 1) & 63;
    int c    = (idx >> 7) & 31;
    int n    = idx >> 12;
    ((float4*)Wt)[idx] =
        ((const float4*)W)[(((n * 64 + r) * 32 + c) << 1) + half];
}

// Routing stage 1. lane == r (64); wave owns one n; G=4 batch elems/block.
// Reductions: halving reduce-scatter + LDS broadcast-back.
__global__ __launch_bounds__(256)
void routing1_reg(const float* __restrict__ h3, const float* __restrict__ Wt,
                  float* __restrict__ v1)
{
    constexpr int C = 32, R = 64, O = 8, G = 4;
    __shared__ float sh[4][48];   // per wave: [0..3] mx, [4..7] sum, [8..40) v

    const int lane = threadIdx.x & 63;
    const int wv   = threadIdx.x >> 6;
    const int n    = blockIdx.y * 4 + wv;
    const int b0   = blockIdx.x * G;

    float u[G][O];
#pragma unroll
    for (int g = 0; g < G; ++g)
#pragma unroll
        for (int o = 0; o < O; ++o) u[g][o] = 0.f;

    const float4* wp = (const float4*)Wt + (size_t)n * C * R * 2;
    const float* xb = h3 + (size_t)b0 * (C * R) + lane;

#pragma unroll 4
    for (int c = 0; c < C; ++c) {
        float xv[G];
#pragma unroll
        for (int g = 0; g < G; ++g) xv[g] = xb[(size_t)g * (C * R) + c * R];
        float4 w0 = wp[(c * R + lane) * 2];
        float4 w1 = wp[(c * R + lane) * 2 + 1];
#pragma unroll
        for (int g = 0; g < G; ++g) {
            u[g][0] = fmaf(xv[g], w0.x, u[g][0]);
            u[g][1] = fmaf(xv[g], w0.y, u[g][1]);
            u[g][2] = fmaf(xv[g], w0.z, u[g][2]);
            u[g][3] = fmaf(xv[g], w0.w, u[g][3]);
            u[g][4] = fmaf(xv[g], w1.x, u[g][4]);
            u[g][5] = fmaf(xv[g], w1.y, u[g][5]);
            u[g][6] = fmaf(xv[g], w1.z, u[g][6]);
            u[g][7] = fmaf(xv[g], w1.w, u[g][7]);
        }
    }

    float bij[G] = {0.f, 0.f, 0.f, 0.f};
    float v_own = 0.f;

    for (int it = 0; it < 3; ++it) {
        // --- softmax over r per g ---
        float t4[G];
#pragma unroll
        for (int g = 0; g < G; ++g) t4[g] = bij[g];
        float mred = halve_max<G>(t4, lane);            // lane: mx for g=lane&3
        if (lane < G) sh[wv][lane] = mred;
        lds_fence();
        float4 mx4 = *(const float4*)&sh[wv][0];
        const float* mxp = (const float*)&mx4;
        float e[G];
#pragma unroll
        for (int g = 0; g < G; ++g) {
            e[g] = __expf(bij[g] - mxp[g]);
            t4[g] = e[g];
        }
        float sred = halve_sum<G>(t4, lane);            // lane: sum for g=lane&3
        if (lane < G) sh[wv][4 + lane] = sred;
        lds_fence();
        float4 sm4 = *(const float4*)&sh[wv][4];
        const float* smp = (const float*)&sm4;
        float cc[G];
#pragma unroll
        for (int g = 0; g < G; ++g) cc[g] = e[g] / smp[g];

        // --- s_j: reduce-scatter 32 values over 64 lanes ---
        float t32[G * O];
#pragma unroll
        for (int g = 0; g < G; ++g)
#pragma unroll
            for (int o = 0; o < O; ++o) t32[g * O + o] = cc[g] * u[g][o];
        float s_own = halve_sum<G * O>(t32, lane);      // j = lane&31: g=j>>3,o=j&7

        // --- squash (norm over o: lanes differing in bits 0..2) ---
        float nr = s_own * s_own;
#pragma unroll
        for (int m = 1; m < O; m <<= 1) nr += __shfl_xor(nr, m, 64);
        float scale = nr / (1.f + nr) / sqrtf(nr + 1e-9f);
        v_own = s_own * scale;

        if (it < 2) {
            if (lane < G * O) sh[wv][8 + lane] = v_own;
            lds_fence();
            const float4* vr4 = (const float4*)&sh[wv][8];
#pragma unroll
            for (int g = 0; g < G; ++g) {
                float4 a = vr4[g * 2], bq = vr4[g * 2 + 1];
                float d = 0.f;
                d = fmaf(u[g][0], a.x, d);  d = fmaf(u[g][1], a.y, d);
                d = fmaf(u[g][2], a.z, d);  d = fmaf(u[g][3], a.w, d);
                d = fmaf(u[g][4], bq.x, d); d = fmaf(u[g][5], bq.y, d);
                d = fmaf(u[g][6], bq.z, d); d = fmaf(u[g][7], bq.w, d);
                bij[g] += d;
            }
        }
    }
    if (lane < G * O) {
        int g = lane >> 3, o = lane & 7;
        v1[(size_t)(b0 + g) * 256 + n * 8 + o] = v_own;
    }
}

// Routing stage 2 + FC. One block per b, 4 waves; lane=(nh, r=lane&31).
// wave wv covers n = wv*4 + p*2 + nh, p=0,1 (n==15 dup masked).
__global__ __launch_bounds__(256)
void routing2_fc(const float* __restrict__ v1, const float* __restrict__ W,
                 const float* __restrict__ fcw, const float* __restrict__ fcb,
                 float* __restrict__ out)
{
    constexpr int R = 32, C = 8, O = 16;
    __shared__ float vv[240];
    __shared__ float sh2[4][64];

    const int t  = threadIdx.x;
    const int b  = blockIdx.x;
    const int wv = t >> 6;
    const int lane = t & 63;
    const int nh = lane >> 5;
    const int r  = lane & 31;

    const float4* xr = (const float4*)(v1 + (size_t)b * 256 + r * 8);
    float4 x0 = xr[0], x1 = xr[1];
    float xv[8] = {x0.x, x0.y, x0.z, x0.w, x1.x, x1.y, x1.z, x1.w};

    float u[2][O];
    int nn[2];
#pragma unroll
    for (int p = 0; p < 2; ++p) {
        int n = wv * 4 + p * 2 + nh;
        nn[p] = n;
        int ncl = n < 15 ? n : 14;
        const float4* wp = (const float4*)(W + ((size_t)(ncl * R + r) * C) * O);
#pragma unroll
        for (int o = 0; o < O; ++o) u[p][o] = 0.f;
#pragma unroll
        for (int c = 0; c < C; ++c) {
#pragma unroll
            for (int j = 0; j < 4; ++j) {
                float4 w4 = wp[c * 4 + j];
                u[p][j * 4 + 0] = fmaf(xv[c], w4.x, u[p][j * 4 + 0]);
                u[p][j * 4 + 1] = fmaf(xv[c], w4.y, u[p][j * 4 + 1]);
                u[p][j * 4 + 2] = fmaf(xv[c], w4.z, u[p][j * 4 + 2]);
                u[p][j * 4 + 3] = fmaf(xv[c], w4.w, u[p][j * 4 + 3]);
            }
        }
    }

    float bij[2] = {0.f, 0.f};
    float v_own = 0.f;
    const int po = r >> 4;          // which p this lane's scatter result is for
    const int oo = r & 15;

    for (int it = 0; it < 3; ++it) {
        float cc[2];
#pragma unroll
        for (int p = 0; p < 2; ++p) {
            float mx = bij[p];
#pragma unroll
            for (int w = 1; w < 32; w <<= 1) mx = fmaxf(mx, __shfl_xor(mx, w, 64));
            float e = __expf(bij[p] - mx);
            float sum = e;
#pragma unroll
            for (int w = 1; w < 32; w <<= 1) sum += __shfl_xor(sum, w, 64);
            cc[p] = e / sum;
        }
        // s_j reduce-scatter: 32 values (p,o) over the 32 lanes of this nh-half
        float t32[32];
#pragma unroll
        for (int p = 0; p < 2; ++p)
#pragma unroll
            for (int o = 0; o < O; ++o) t32[p * O + o] = cc[p] * u[p][o];
        // halving masks 16..1 stay within the nh half
        float s_own;
        {
#pragma unroll
            for (int m = 16; m >= 1; m >>= 1) {
                bool hi = (r & m) != 0;
#pragma unroll
                for (int j = 0; j < m; ++j) {
                    float keep = hi ? t32[j + m] : t32[j];
                    float send = hi ? t32[j] : t32[j + m];
                    t32[j] = keep + __shfl_xor(send, m, 64);
                }
            }
            s_own = t32[0];      // lane: s for p=r>>4, o=r&15 (its nh's n)
        }
        // squash: norm over o (lanes differing in bits 0..3)
        float nr = s_own * s_own;
#pragma unroll
        for (int m = 1; m < O; m <<= 1) nr += __shfl_xor(nr, m, 64);
        float scale = nr / (1.f + nr) / sqrtf(nr + 1e-9f);
        v_own = s_own * scale;

        if (it < 2) {
            sh2[wv][lane] = v_own;       // [nh*32 + p*16 + o]
            lds_fence();
            const float4* vr4 = (const float4*)&sh2[wv][nh * 32];
#pragma unroll
            for (int p = 0; p < 2; ++p) {
                float d = 0.f;
#pragma unroll
                for (int j = 0; j < 4; ++j) {
                    float4 a = vr4[p * 4 + j];
                    d = fmaf(u[p][j * 4 + 0], a.x, d);
                    d = fmaf(u[p][j * 4 + 1], a.y, d);
                    d = fmaf(u[p][j * 4 + 2], a.z, d);
                    d = fmaf(u[p][j * 4 + 3], a.w, d);
                }
                bij[p] += d;
            }
        }
    }
    {
        int n = wv * 4 + po * 2 + nh;
        if (n < 15) vv[n * O + oo] = v_own;
    }
    __syncthreads();
    if (t < 240) {
        int j = t >> 4, k0 = t & 15;
        float acc = 0.f;
        for (int k = k0; k < 240; k += 16) acc = fmaf(vv[k], fcw[j * 240 + k], acc);
#pragma unroll
        for (int w = 1; w < 16; w <<= 1) acc += __shfl_xor(acc, w, 16);
        if (k0 == 0) out[(size_t)b * 15 + j] = acc + fcb[j];
    }
}

extern "C" void kernel_launch(void* const* d_in, const int* in_sizes, int n_in,
                              void* d_out, int out_size, void* d_ws, size_t ws_size,
                              hipStream_t stream) {
    const float* x    = (const float*)d_in[0];
    const float* w1   = (const float*)d_in[1];
    const float* b1   = (const float*)d_in[2];
    const float* w2   = (const float*)d_in[3];
    const float* b2   = (const float*)d_in[4];
    const float* w3   = (const float*)d_in[5];
    const float* b3   = (const float*)d_in[6];
    const float* rw1  = (const float*)d_in[7];
    const float* rw2  = (const float*)d_in[8];
    const float* fcw  = (const float*)d_in[9];
    const float* fcb  = (const float*)d_in[10];
    float* out = (float*)d_out;

    const int B = 512;
    float* ws = (float*)d_ws;
    float* h1 = ws;                                  // [512,8,32,32]
    float* h2 = h1 + (size_t)B * 8 * 32 * 32;        // [512,16,16,16] (dead after conv3)
    float* h3 = h2 + (size_t)B * 16 * 16 * 16;       // [512,32,8,8]
    float* v1 = h3 + (size_t)B * 32 * 8 * 8;         // [512,32,8]
    float* Wt = h2;                                  // rw1 transposed, reuses h2

    conv_relu_pool<3, 8, 64, 2, 8><<<dim3(B, 4), 256, 0, stream>>>(x, w1, b1, h1);
    conv_relu_pool<8, 16, 32, 2, 8><<<dim3(B, 2), 256, 0, stream>>>(h1, w2, b2, h2);
    conv_relu_pool<16, 32, 16, 2, 8><<<dim3(B, 1), 256, 0, stream>>>(h2, w3, b3, h3);
    transpose_w1<<<(32 * 32 * 64 * 2 + 255) / 256, 256, 0, stream>>>(rw1, Wt);
    {
        dim3 grid(B / 4, 8);
        routing1_reg<<<grid, 256, 0, stream>>>(h3, Wt, v1);
    }
    routing2_fc<<<B, 256, 0, stream>>>(v1, rw2, fcw, fcb, out);
}

// Round 6
// 223.726 us; speedup vs baseline: 1.7342x; 1.7342x over previous
//
#include <hip/hip_runtime.h>
#include <hip/hip_bf16.h>

// ---------------------------------------------------------------------------
// CapsNet forward, fp32. B=512.
// convs: one block per batch elem, padded input in LDS, fused relu+pool.
// routing1: register-resident, lane==route(64), full butterfly reductions,
//           G=2 batch elems/block -> 2048 blocks (8/CU) for latency hiding.
// routing2+fc: register-resident, 32-lane butterflies.
// Iter-0 softmax of b_ij==0 is uniform -> constant c (exact).
// ---------------------------------------------------------------------------

template<int CIN, int COUT, int HIN, int NO>
__global__ __launch_bounds__(256)
void conv_relu_pool(const float* __restrict__ in, const float* __restrict__ w,
                    const float* __restrict__ bias, float* __restrict__ out)
{
    constexpr int HOUT = HIN / 2;
    constexpr int PR = HIN + 2;
    constexpr int PC = (HIN + 2 + 3) & ~3;
    constexpr int NS = HIN / 8;
    constexpr int NOP = COUT / NO;
    constexpr int NTASK = NOP * HOUT * NS;
    constexpr int XWORDS = CIN * PR * PC;
    constexpr int WWORDS = CIN * 9 * COUT;

    __shared__ float xin[CIN][PR][PC];
    __shared__ float wt[WWORDS];                // [c][k][o]
    __shared__ float bl[COUT];

    const int tid = threadIdx.x;
    const int b   = blockIdx.x;

    for (int i = tid; i < XWORDS; i += 256) ((float*)xin)[i] = 0.f;
    for (int i = tid; i < WWORDS; i += 256) {
        int o = i % COUT, k = (i / COUT) % 9, c = i / (COUT * 9);
        wt[i] = w[(o * CIN + c) * 9 + k];
    }
    if (tid < COUT) bl[tid] = bias[tid];
    __syncthreads();

    const float4* gin = (const float4*)(in + (size_t)b * CIN * HIN * HIN);
    constexpr int CHUNKS = CIN * HIN * (HIN / 4);
    for (int i = tid; i < CHUNKS; i += 256) {
        float4 v = gin[i];
        int ch = i % (HIN / 4);
        int y  = (i / (HIN / 4)) % HIN;
        int c  = i / ((HIN / 4) * HIN);
        float* dst = &xin[c][y + 1][ch * 4 + 1];
        dst[0] = v.x; dst[1] = v.y; dst[2] = v.z; dst[3] = v.w;
    }
    __syncthreads();

    for (int task = tid; task < NTASK; task += 256) {
        const int s  = task % NS;
        const int py = (task / NS) % HOUT;
        const int o0 = (task / (NS * HOUT)) * NO;
        const int X0 = s * 8;

        float acc[NO][2][8];
#pragma unroll
        for (int n = 0; n < NO; ++n)
#pragma unroll
            for (int q = 0; q < 2; ++q)
#pragma unroll
                for (int j = 0; j < 8; ++j) acc[n][q][j] = 0.f;

        for (int c = 0; c < CIN; ++c) {
            float rows[4][12];
#pragma unroll
            for (int rr = 0; rr < 4; ++rr) {
                const float4* src = (const float4*)&xin[c][2 * py + rr][X0];
#pragma unroll
                for (int j = 0; j < 3; ++j) {
                    float4 v = src[j];
                    rows[rr][j * 4 + 0] = v.x; rows[rr][j * 4 + 1] = v.y;
                    rows[rr][j * 4 + 2] = v.z; rows[rr][j * 4 + 3] = v.w;
                }
            }
            const float* wc = wt + c * 9 * COUT;
#pragma unroll
            for (int ky = 0; ky < 3; ++ky) {
#pragma unroll
                for (int n = 0; n < NO; ++n) {
                    const float w0 = wc[(ky * 3 + 0) * COUT + o0 + n];
                    const float w1 = wc[(ky * 3 + 1) * COUT + o0 + n];
                    const float w2 = wc[(ky * 3 + 2) * COUT + o0 + n];
#pragma unroll
                    for (int j = 0; j < 8; ++j) {
                        acc[n][0][j] = fmaf(rows[ky][j],     w0, acc[n][0][j]);
                        acc[n][0][j] = fmaf(rows[ky][j + 1], w1, acc[n][0][j]);
                        acc[n][0][j] = fmaf(rows[ky][j + 2], w2, acc[n][0][j]);
                        acc[n][1][j] = fmaf(rows[ky + 1][j],     w0, acc[n][1][j]);
                        acc[n][1][j] = fmaf(rows[ky + 1][j + 1], w1, acc[n][1][j]);
                        acc[n][1][j] = fmaf(rows[ky + 1][j + 2], w2, acc[n][1][j]);
                    }
                }
            }
        }
#pragma unroll
        for (int n = 0; n < NO; ++n) {
            const float bv = bl[o0 + n];
            float4 ov;
            float* p = (float*)&ov;
#pragma unroll
            for (int j = 0; j < 4; ++j) {
                float m = fmaxf(fmaxf(acc[n][0][2 * j], acc[n][0][2 * j + 1]),
                                fmaxf(acc[n][1][2 * j], acc[n][1][2 * j + 1]));
                p[j] = fmaxf(m + bv, 0.f);
            }
            float* po = out + (((size_t)b * COUT + o0 + n) * HOUT + py) * HOUT + s * 4;
            *(float4*)po = ov;
        }
    }
}

// W[n][r][c][o] -> Wt[n][c][r][o]  (n=32, r=64, c=32, o=8), float4 granules.
__global__ __launch_bounds__(256)
void transpose_w1(const float* __restrict__ W, float* __restrict__ Wt)
{
    int idx = blockIdx.x * 256 + threadIdx.x;
    if (idx >= 32 * 32 * 64 * 2) return;
    int half = idx & 1;
    int r    = (idx >> 1) & 63;
    int c    = (idx >> 7) & 31;
    int n    = idx >> 12;
    ((float4*)Wt)[idx] =
        ((const float4*)W)[(((n * 64 + r) * 32 + c) << 1) + half];
}

// Routing stage 1, register-resident. lane == r; wave owns one n; G=2 b/block.
// Grid (B/2, 8) = 2048 blocks -> 8 blocks/CU.
__global__ __launch_bounds__(256)
void routing1_reg(const float* __restrict__ h3, const float* __restrict__ Wt,
                  float* __restrict__ v1)
{
    constexpr int C = 32, R = 64, O = 8, G = 2;
    const int lane = threadIdx.x & 63;
    const int n    = blockIdx.y * 4 + (threadIdx.x >> 6);
    const int b0   = blockIdx.x * G;

    float u[G][O];
#pragma unroll
    for (int g = 0; g < G; ++g)
#pragma unroll
        for (int o = 0; o < O; ++o) u[g][o] = 0.f;

    const float4* wp = (const float4*)Wt + (size_t)n * C * R * 2;
    const float* xb = h3 + (size_t)b0 * (C * R) + lane;

#pragma unroll 4
    for (int c = 0; c < C; ++c) {
        float xv[G];
#pragma unroll
        for (int g = 0; g < G; ++g) xv[g] = xb[(size_t)g * (C * R) + c * R];
        float4 w0 = wp[(c * R + lane) * 2];
        float4 w1 = wp[(c * R + lane) * 2 + 1];
#pragma unroll
        for (int g = 0; g < G; ++g) {
            u[g][0] = fmaf(xv[g], w0.x, u[g][0]);
            u[g][1] = fmaf(xv[g], w0.y, u[g][1]);
            u[g][2] = fmaf(xv[g], w0.z, u[g][2]);
            u[g][3] = fmaf(xv[g], w0.w, u[g][3]);
            u[g][4] = fmaf(xv[g], w1.x, u[g][4]);
            u[g][5] = fmaf(xv[g], w1.y, u[g][5]);
            u[g][6] = fmaf(xv[g], w1.z, u[g][6]);
            u[g][7] = fmaf(xv[g], w1.w, u[g][7]);
        }
    }

    float bij[G];
#pragma unroll
    for (int g = 0; g < G; ++g) bij[g] = 0.f;
    float s[G][O];

#pragma unroll
    for (int it = 0; it < 3; ++it) {
        float cc[G];
        if (it == 0) {
            // softmax(0) over 64 routes is exactly uniform
#pragma unroll
            for (int g = 0; g < G; ++g) cc[g] = 1.0f / 64.0f;
        } else {
#pragma unroll
            for (int g = 0; g < G; ++g) {
                float mx = bij[g];
#pragma unroll
                for (int w = 1; w < 64; w <<= 1) mx = fmaxf(mx, __shfl_xor(mx, w, 64));
                float e = __expf(bij[g] - mx);
                float sum = e;
#pragma unroll
                for (int w = 1; w < 64; w <<= 1) sum += __shfl_xor(sum, w, 64);
                cc[g] = e / sum;
            }
        }
#pragma unroll
        for (int g = 0; g < G; ++g)
#pragma unroll
            for (int o = 0; o < O; ++o) s[g][o] = cc[g] * u[g][o];
#pragma unroll
        for (int w = 1; w < 64; w <<= 1)
#pragma unroll
            for (int g = 0; g < G; ++g)
#pragma unroll
                for (int o = 0; o < O; ++o) s[g][o] += __shfl_xor(s[g][o], w, 64);
#pragma unroll
        for (int g = 0; g < G; ++g) {
            float nr = 0.f;
#pragma unroll
            for (int o = 0; o < O; ++o) nr = fmaf(s[g][o], s[g][o], nr);
            float scale = nr / (1.f + nr) / sqrtf(nr + 1e-9f);
#pragma unroll
            for (int o = 0; o < O; ++o) s[g][o] *= scale;   // s is now v
            if (it < 2) {
                float d = 0.f;
#pragma unroll
                for (int o = 0; o < O; ++o) d = fmaf(u[g][o], s[g][o], d);
                bij[g] += d;
            }
        }
    }
    // each lane writes one (g,o); values identical across lanes
    float outv = 0.f;
#pragma unroll
    for (int g = 0; g < G; ++g)
#pragma unroll
        for (int o = 0; o < O; ++o)
            outv = (lane == g * O + o) ? s[g][o] : outv;
    if (lane < G * O)
        v1[(size_t)(b0 + (lane >> 3)) * 256 + n * 8 + (lane & 7)] = outv;
}

// Routing stage 2 + FC, register-resident. One block per b, 4 waves.
// lane = (nh, r): nh = lane>>5, r = lane&31 (R=32).
// wave wv covers n = wv*4 + p*2 + nh for p=0,1 (n==15 dup masked).
__global__ __launch_bounds__(256)
void routing2_fc(const float* __restrict__ v1, const float* __restrict__ W,
                 const float* __restrict__ fcw, const float* __restrict__ fcb,
                 float* __restrict__ out)
{
    constexpr int R = 32, C = 8, O = 16;
    __shared__ float vv[240];

    const int t  = threadIdx.x;
    const int b  = blockIdx.x;
    const int wv = t >> 6;
    const int lane = t & 63;
    const int nh = lane >> 5;
    const int r  = lane & 31;

    const float4* xr = (const float4*)(v1 + (size_t)b * 256 + r * 8);
    float4 x0 = xr[0], x1 = xr[1];
    float xv[8] = {x0.x, x0.y, x0.z, x0.w, x1.x, x1.y, x1.z, x1.w};

    float u[2][O];
    int nn[2];
#pragma unroll
    for (int p = 0; p < 2; ++p) {
        int n = wv * 4 + p * 2 + nh;
        nn[p] = n;
        int ncl = n < 15 ? n : 14;
        const float4* wp = (const float4*)(W + ((size_t)(ncl * R + r) * C) * O);
#pragma unroll
        for (int o = 0; o < O; ++o) u[p][o] = 0.f;
#pragma unroll
        for (int c = 0; c < C; ++c) {
#pragma unroll
            for (int j = 0; j < 4; ++j) {
                float4 w4 = wp[c * 4 + j];
                u[p][j * 4 + 0] = fmaf(xv[c], w4.x, u[p][j * 4 + 0]);
                u[p][j * 4 + 1] = fmaf(xv[c], w4.y, u[p][j * 4 + 1]);
                u[p][j * 4 + 2] = fmaf(xv[c], w4.z, u[p][j * 4 + 2]);
                u[p][j * 4 + 3] = fmaf(xv[c], w4.w, u[p][j * 4 + 3]);
            }
        }
    }

    float bij[2] = {0.f, 0.f};
    float s[2][O];
#pragma unroll
    for (int it = 0; it < 3; ++it) {
#pragma unroll
        for (int p = 0; p < 2; ++p) {
            float cc;
            if (it == 0) {
                cc = 1.0f / 32.0f;    // softmax(0) over 32 routes, exact
            } else {
                float mx = bij[p];
#pragma unroll
                for (int w = 1; w < 32; w <<= 1) mx = fmaxf(mx, __shfl_xor(mx, w, 32));
                float e = __expf(bij[p] - mx);
                float sum = e;
#pragma unroll
                for (int w = 1; w < 32; w <<= 1) sum += __shfl_xor(sum, w, 32);
                cc = e / sum;
            }
#pragma unroll
            for (int o = 0; o < O; ++o) s[p][o] = cc * u[p][o];
        }
#pragma unroll
        for (int w = 1; w < 32; w <<= 1)
#pragma unroll
            for (int p = 0; p < 2; ++p)
#pragma unroll
                for (int o = 0; o < O; ++o) s[p][o] += __shfl_xor(s[p][o], w, 32);
#pragma unroll
        for (int p = 0; p < 2; ++p) {
            float nr = 0.f;
#pragma unroll
            for (int o = 0; o < O; ++o) nr = fmaf(s[p][o], s[p][o], nr);
            float scale = nr / (1.f + nr) / sqrtf(nr + 1e-9f);
#pragma unroll
            for (int o = 0; o < O; ++o) s[p][o] *= scale;   // s is now v
            if (it < 2) {
                float d = 0.f;
#pragma unroll
                for (int o = 0; o < O; ++o) d = fmaf(u[p][o], s[p][o], d);
                bij[p] += d;
            }
        }
    }
#pragma unroll
    for (int p = 0; p < 2; ++p) {
        float outv = 0.f;
#pragma unroll
        for (int o = 0; o < O; ++o) outv = (r == o) ? s[p][o] : outv;
        if (r < O && nn[p] < 15) vv[nn[p] * O + r] = outv;
    }
    __syncthreads();
    if (t < 240) {
        int j = t >> 4, k0 = t & 15;
        float acc = 0.f;
        for (int k = k0; k < 240; k += 16) acc = fmaf(vv[k], fcw[j * 240 + k], acc);
#pragma unroll
        for (int w = 1; w < 16; w <<= 1) acc += __shfl_xor(acc, w, 16);
        if (k0 == 0) out[(size_t)b * 15 + j] = acc + fcb[j];
    }
}

extern "C" void kernel_launch(void* const* d_in, const int* in_sizes, int n_in,
                              void* d_out, int out_size, void* d_ws, size_t ws_size,
                              hipStream_t stream) {
    const float* x    = (const float*)d_in[0];
    const float* w1   = (const float*)d_in[1];
    const float* b1   = (const float*)d_in[2];
    const float* w2   = (const float*)d_in[3];
    const float* b2   = (const float*)d_in[4];
    const float* w3   = (const float*)d_in[5];
    const float* b3   = (const float*)d_in[6];
    const float* rw1  = (const float*)d_in[7];
    const float* rw2  = (const float*)d_in[8];
    const float* fcw  = (const float*)d_in[9];
    const float* fcb  = (const float*)d_in[10];
    float* out = (float*)d_out;

    const int B = 512;
    float* ws = (float*)d_ws;
    float* h1 = ws;                                  // [512,8,32,32]
    float* h2 = h1 + (size_t)B * 8 * 32 * 32;        // [512,16,16,16] (dead after conv3)
    float* h3 = h2 + (size_t)B * 16 * 16 * 16;       // [512,32,8,8]
    float* v1 = h3 + (size_t)B * 32 * 8 * 8;         // [512,32,8]
    float* Wt = h2;                                  // rw1 transposed, reuses h2

    conv_relu_pool<3, 8, 64, 4><<<B, 256, 0, stream>>>(x, w1, b1, h1);
    conv_relu_pool<8, 16, 32, 4><<<B, 256, 0, stream>>>(h1, w2, b2, h2);
    conv_relu_pool<16, 32, 16, 2><<<B, 256, 0, stream>>>(h2, w3, b3, h3);
    transpose_w1<<<(32 * 32 * 64 * 2 + 255) / 256, 256, 0, stream>>>(rw1, Wt);
    {
        dim3 grid(B / 2, 8);
        routing1_reg<<<grid, 256, 0, stream>>>(h3, Wt, v1);
    }
    routing2_fc<<<B, 256, 0, stream>>>(v1, rw2, fcw, fcb, out);
}

// Round 8
// 213.380 us; speedup vs baseline: 1.8183x; 1.0485x over previous
//
#include <hip/hip_runtime.h>
#include <hip/hip_bf16.h>

// ---------------------------------------------------------------------------
// CapsNet forward, fp32. B=512.
// convs: one block per batch elem, padded input in LDS, fused relu+pool.
// routing1 SPLIT:
//   K1 routing1_einsum: lane==r, wave==n, G=8 b/block; W reuse x8; u_hat -> ws.
//   K2 routing1_iter: thread=(n, r-octet): u in 64 regs, softmax/s_j via
//      8-lane reduces, squash + b_ij update pure per-thread register math.
// routing2+fc: register-resident, 32-lane butterflies (unchanged).
// ---------------------------------------------------------------------------

template<int CIN, int COUT, int HIN, int NO>
__global__ __launch_bounds__(256)
void conv_relu_pool(const float* __restrict__ in, const float* __restrict__ w,
                    const float* __restrict__ bias, float* __restrict__ out)
{
    constexpr int HOUT = HIN / 2;
    constexpr int PR = HIN + 2;
    constexpr int PC = (HIN + 2 + 3) & ~3;
    constexpr int NS = HIN / 8;
    constexpr int NOP = COUT / NO;
    constexpr int NTASK = NOP * HOUT * NS;
    constexpr int XWORDS = CIN * PR * PC;
    constexpr int WWORDS = CIN * 9 * COUT;

    __shared__ float xin[CIN][PR][PC];
    __shared__ float wt[WWORDS];                // [c][k][o]
    __shared__ float bl[COUT];

    const int tid = threadIdx.x;
    const int b   = blockIdx.x;

    for (int i = tid; i < XWORDS; i += 256) ((float*)xin)[i] = 0.f;
    for (int i = tid; i < WWORDS; i += 256) {
        int o = i % COUT, k = (i / COUT) % 9, c = i / (COUT * 9);
        wt[i] = w[(o * CIN + c) * 9 + k];
    }
    if (tid < COUT) bl[tid] = bias[tid];
    __syncthreads();

    const float4* gin = (const float4*)(in + (size_t)b * CIN * HIN * HIN);
    constexpr int CHUNKS = CIN * HIN * (HIN / 4);
    for (int i = tid; i < CHUNKS; i += 256) {
        float4 v = gin[i];
        int ch = i % (HIN / 4);
        int y  = (i / (HIN / 4)) % HIN;
        int c  = i / ((HIN / 4) * HIN);
        float* dst = &xin[c][y + 1][ch * 4 + 1];
        dst[0] = v.x; dst[1] = v.y; dst[2] = v.z; dst[3] = v.w;
    }
    __syncthreads();

    for (int task = tid; task < NTASK; task += 256) {
        const int s  = task % NS;
        const int py = (task / NS) % HOUT;
        const int o0 = (task / (NS * HOUT)) * NO;
        const int X0 = s * 8;

        float acc[NO][2][8];
#pragma unroll
        for (int n = 0; n < NO; ++n)
#pragma unroll
            for (int q = 0; q < 2; ++q)
#pragma unroll
                for (int j = 0; j < 8; ++j) acc[n][q][j] = 0.f;

        for (int c = 0; c < CIN; ++c) {
            float rows[4][12];
#pragma unroll
            for (int rr = 0; rr < 4; ++rr) {
                const float4* src = (const float4*)&xin[c][2 * py + rr][X0];
#pragma unroll
                for (int j = 0; j < 3; ++j) {
                    float4 v = src[j];
                    rows[rr][j * 4 + 0] = v.x; rows[rr][j * 4 + 1] = v.y;
                    rows[rr][j * 4 + 2] = v.z; rows[rr][j * 4 + 3] = v.w;
                }
            }
            const float* wc = wt + c * 9 * COUT;
#pragma unroll
            for (int ky = 0; ky < 3; ++ky) {
#pragma unroll
                for (int n = 0; n < NO; ++n) {
                    const float w0 = wc[(ky * 3 + 0) * COUT + o0 + n];
                    const float w1 = wc[(ky * 3 + 1) * COUT + o0 + n];
                    const float w2 = wc[(ky * 3 + 2) * COUT + o0 + n];
#pragma unroll
                    for (int j = 0; j < 8; ++j) {
                        acc[n][0][j] = fmaf(rows[ky][j],     w0, acc[n][0][j]);
                        acc[n][0][j] = fmaf(rows[ky][j + 1], w1, acc[n][0][j]);
                        acc[n][0][j] = fmaf(rows[ky][j + 2], w2, acc[n][0][j]);
                        acc[n][1][j] = fmaf(rows[ky + 1][j],     w0, acc[n][1][j]);
                        acc[n][1][j] = fmaf(rows[ky + 1][j + 1], w1, acc[n][1][j]);
                        acc[n][1][j] = fmaf(rows[ky + 1][j + 2], w2, acc[n][1][j]);
                    }
                }
            }
        }
#pragma unroll
        for (int n = 0; n < NO; ++n) {
            const float bv = bl[o0 + n];
            float4 ov;
            float* p = (float*)&ov;
#pragma unroll
            for (int j = 0; j < 4; ++j) {
                float m = fmaxf(fmaxf(acc[n][0][2 * j], acc[n][0][2 * j + 1]),
                                fmaxf(acc[n][1][2 * j], acc[n][1][2 * j + 1]));
                p[j] = fmaxf(m + bv, 0.f);
            }
            float* po = out + (((size_t)b * COUT + o0 + n) * HOUT + py) * HOUT + s * 4;
            *(float4*)po = ov;
        }
    }
}

// W[n][r][c][o] -> Wt[n][c][r][o]  (n=32, r=64, c=32, o=8), float4 granules.
__global__ __launch_bounds__(256)
void transpose_w1(const float* __restrict__ W, float* __restrict__ Wt)
{
    int idx = blockIdx.x * 256 + threadIdx.x;
    if (idx >= 32 * 32 * 64 * 2) return;
    int half = idx & 1;
    int r    = (idx >> 1) & 63;
    int c    = (idx >> 7) & 31;
    int n    = idx >> 12;
    ((float4*)Wt)[idx] =
        ((const float4*)W)[(((n * 64 + r) * 32 + c) << 1) + half];
}

// K1: u_hat einsum. lane==r, wave==n (quad), G=8 batch elems per block.
// uhat[b][n][r][o], fully dense coalesced stores.
__global__ __launch_bounds__(256)
void routing1_einsum(const float* __restrict__ h3, const float* __restrict__ Wt,
                     float* __restrict__ uhat)
{
    constexpr int C = 32, R = 64, O = 8, G = 8;
    const int lane = threadIdx.x & 63;
    const int n    = blockIdx.y * 4 + (threadIdx.x >> 6);
    const int b0   = blockIdx.x * G;

    float u[G][O];
#pragma unroll
    for (int g = 0; g < G; ++g)
#pragma unroll
        for (int o = 0; o < O; ++o) u[g][o] = 0.f;

    const float4* wp = (const float4*)Wt + (size_t)n * C * R * 2;
    const float* xb = h3 + (size_t)b0 * (C * R) + lane;

#pragma unroll 4
    for (int c = 0; c < C; ++c) {
        float xv[G];
#pragma unroll
        for (int g = 0; g < G; ++g) xv[g] = xb[(size_t)g * (C * R) + c * R];
        float4 w0 = wp[(c * R + lane) * 2];
        float4 w1 = wp[(c * R + lane) * 2 + 1];
#pragma unroll
        for (int g = 0; g < G; ++g) {
            u[g][0] = fmaf(xv[g], w0.x, u[g][0]);
            u[g][1] = fmaf(xv[g], w0.y, u[g][1]);
            u[g][2] = fmaf(xv[g], w0.z, u[g][2]);
            u[g][3] = fmaf(xv[g], w0.w, u[g][3]);
            u[g][4] = fmaf(xv[g], w1.x, u[g][4]);
            u[g][5] = fmaf(xv[g], w1.y, u[g][5]);
            u[g][6] = fmaf(xv[g], w1.z, u[g][6]);
            u[g][7] = fmaf(xv[g], w1.w, u[g][7]);
        }
    }
#pragma unroll
    for (int g = 0; g < G; ++g) {
        float4* dst = (float4*)(uhat + (((size_t)(b0 + g) * 32 + n) * R + lane) * O);
        dst[0] = make_float4(u[g][0], u[g][1], u[g][2], u[g][3]);
        dst[1] = make_float4(u[g][4], u[g][5], u[g][6], u[g][7]);
    }
}

// K2: routing iterations. One block per b; thread = (n, rp): owns r = rp*8..+7,
// all o. u in 64 regs (16 coalesced float4 loads). Cross-lane only for the
// 8-wide softmax/s_j reduces (xor masks 1,2,4 stay inside the n-group).
__global__ __launch_bounds__(256)
void routing1_iter(const float* __restrict__ uhat, float* __restrict__ v1)
{
    constexpr int O = 8;
    const int t  = threadIdx.x;
    const int b  = blockIdx.x;
    const int n  = t >> 3;
    const int rp = t & 7;

    float u[8][O];
    {
        const float4* up = (const float4*)(uhat + (((size_t)b * 32 + n) * 64 + rp * 8) * O);
#pragma unroll
        for (int i = 0; i < 16; ++i) {
            float4 w = up[i];
            u[i >> 1][(i & 1) * 4 + 0] = w.x;
            u[i >> 1][(i & 1) * 4 + 1] = w.y;
            u[i >> 1][(i & 1) * 4 + 2] = w.z;
            u[i >> 1][(i & 1) * 4 + 3] = w.w;
        }
    }

    float bij[8];
#pragma unroll
    for (int k = 0; k < 8; ++k) bij[k] = 0.f;
    float s[O];

#pragma unroll
    for (int it = 0; it < 3; ++it) {
        float e[8];
        float inv;
        if (it == 0) {
            // softmax(0) over 64 routes is exactly uniform
#pragma unroll
            for (int k = 0; k < 8; ++k) e[k] = 1.f;
            inv = 1.0f / 64.0f;
        } else {
            float mx = bij[0];
#pragma unroll
            for (int k = 1; k < 8; ++k) mx = fmaxf(mx, bij[k]);
#pragma unroll
            for (int m = 1; m < 8; m <<= 1) mx = fmaxf(mx, __shfl_xor(mx, m, 64));
            float sum = 0.f;
#pragma unroll
            for (int k = 0; k < 8; ++k) { e[k] = __expf(bij[k] - mx); sum += e[k]; }
#pragma unroll
            for (int m = 1; m < 8; m <<= 1) sum += __shfl_xor(sum, m, 64);
            inv = 1.f / sum;
        }
        // t[o] = sum_r e_r * u[r][o]  (partial over own 8 r, reduce over rp)
        float ta[O];
#pragma unroll
        for (int o = 0; o < O; ++o) ta[o] = 0.f;
#pragma unroll
        for (int k = 0; k < 8; ++k)
#pragma unroll
            for (int o = 0; o < O; ++o) ta[o] = fmaf(e[k], u[k][o], ta[o]);
#pragma unroll
        for (int m = 1; m < 8; m <<= 1)
#pragma unroll
            for (int o = 0; o < O; ++o) ta[o] += __shfl_xor(ta[o], m, 64);
        // s_j and squash (all per-thread)
        float nr = 0.f;
#pragma unroll
        for (int o = 0; o < O; ++o) { s[o] = ta[o] * inv; nr = fmaf(s[o], s[o], nr); }
        float scale = nr / (1.f + nr) / sqrtf(nr + 1e-9f);
#pragma unroll
        for (int o = 0; o < O; ++o) s[o] *= scale;
        if (it < 2) {
#pragma unroll
            for (int k = 0; k < 8; ++k) {
                float d = 0.f;
#pragma unroll
                for (int o = 0; o < O; ++o) d = fmaf(u[k][o], s[o], d);
                bij[k] += d;
            }
        }
    }
    // v identical across the 8 rp lanes of each n; lane rp writes o=rp.
    float outv = s[0];
#pragma unroll
    for (int o = 1; o < O; ++o) outv = (rp == o) ? s[o] : outv;
    v1[(size_t)b * 256 + n * 8 + rp] = outv;
}

// Routing stage 2 + FC, register-resident. One block per b, 4 waves.
__global__ __launch_bounds__(256)
void routing2_fc(const float* __restrict__ v1, const float* __restrict__ W,
                 const float* __restrict__ fcw, const float* __restrict__ fcb,
                 float* __restrict__ out)
{
    constexpr int R = 32, C = 8, O = 16;
    __shared__ float vv[240];

    const int t  = threadIdx.x;
    const int b  = blockIdx.x;
    const int wv = t >> 6;
    const int lane = t & 63;
    const int nh = lane >> 5;
    const int r  = lane & 31;

    const float4* xr = (const float4*)(v1 + (size_t)b * 256 + r * 8);
    float4 x0 = xr[0], x1 = xr[1];
    float xv[8] = {x0.x, x0.y, x0.z, x0.w, x1.x, x1.y, x1.z, x1.w};

    float u[2][O];
    int nn[2];
#pragma unroll
    for (int p = 0; p < 2; ++p) {
        int n = wv * 4 + p * 2 + nh;
        nn[p] = n;
        int ncl = n < 15 ? n : 14;
        const float4* wp = (const float4*)(W + ((size_t)(ncl * R + r) * C) * O);
#pragma unroll
        for (int o = 0; o < O; ++o) u[p][o] = 0.f;
#pragma unroll
        for (int c = 0; c < C; ++c) {
#pragma unroll
            for (int j = 0; j < 4; ++j) {
                float4 w4 = wp[c * 4 + j];
                u[p][j * 4 + 0] = fmaf(xv[c], w4.x, u[p][j * 4 + 0]);
                u[p][j * 4 + 1] = fmaf(xv[c], w4.y, u[p][j * 4 + 1]);
                u[p][j * 4 + 2] = fmaf(xv[c], w4.z, u[p][j * 4 + 2]);
                u[p][j * 4 + 3] = fmaf(xv[c], w4.w, u[p][j * 4 + 3]);
            }
        }
    }

    float bij[2] = {0.f, 0.f};
    float s[2][O];
#pragma unroll
    for (int it = 0; it < 3; ++it) {
#pragma unroll
        for (int p = 0; p < 2; ++p) {
            float cc;
            if (it == 0) {
                cc = 1.0f / 32.0f;
            } else {
                float mx = bij[p];
#pragma unroll
                for (int w = 1; w < 32; w <<= 1) mx = fmaxf(mx, __shfl_xor(mx, w, 32));
                float e = __expf(bij[p] - mx);
                float sum = e;
#pragma unroll
                for (int w = 1; w < 32; w <<= 1) sum += __shfl_xor(sum, w, 32);
                cc = e / sum;
            }
#pragma unroll
            for (int o = 0; o < O; ++o) s[p][o] = cc * u[p][o];
        }
#pragma unroll
        for (int w = 1; w < 32; w <<= 1)
#pragma unroll
            for (int p = 0; p < 2; ++p)
#pragma unroll
                for (int o = 0; o < O; ++o) s[p][o] += __shfl_xor(s[p][o], w, 32);
#pragma unroll
        for (int p = 0; p < 2; ++p) {
            float nr = 0.f;
#pragma unroll
            for (int o = 0; o < O; ++o) nr = fmaf(s[p][o], s[p][o], nr);
            float scale = nr / (1.f + nr) / sqrtf(nr + 1e-9f);
#pragma unroll
            for (int o = 0; o < O; ++o) s[p][o] *= scale;
            if (it < 2) {
                float d = 0.f;
#pragma unroll
                for (int o = 0; o < O; ++o) d = fmaf(u[p][o], s[p][o], d);
                bij[p] += d;
            }
        }
    }
#pragma unroll
    for (int p = 0; p < 2; ++p) {
        float outv = 0.f;
#pragma unroll
        for (int o = 0; o < O; ++o) outv = (r == o) ? s[p][o] : outv;
        if (r < O && nn[p] < 15) vv[nn[p] * O + r] = outv;
    }
    __syncthreads();
    if (t < 240) {
        int j = t >> 4, k0 = t & 15;
        float acc = 0.f;
        for (int k = k0; k < 240; k += 16) acc = fmaf(vv[k], fcw[j * 240 + k], acc);
#pragma unroll
        for (int w = 1; w < 16; w <<= 1) acc += __shfl_xor(acc, w, 16);
        if (k0 == 0) out[(size_t)b * 15 + j] = acc + fcb[j];
    }
}

extern "C" void kernel_launch(void* const* d_in, const int* in_sizes, int n_in,
                              void* d_out, int out_size, void* d_ws, size_t ws_size,
                              hipStream_t stream) {
    const float* x    = (const float*)d_in[0];
    const float* w1   = (const float*)d_in[1];
    const float* b1   = (const float*)d_in[2];
    const float* w2   = (const float*)d_in[3];
    const float* b2   = (const float*)d_in[4];
    const float* w3   = (const float*)d_in[5];
    const float* b3   = (const float*)d_in[6];
    const float* rw1  = (const float*)d_in[7];
    const float* rw2  = (const float*)d_in[8];
    const float* fcw  = (const float*)d_in[9];
    const float* fcb  = (const float*)d_in[10];
    float* out = (float*)d_out;

    const int B = 512;
    float* ws = (float*)d_ws;
    // Memory map (floats). uhat overlays h1+h2 (dead after conv3).
    float* uhat = ws;                                // [512,32,64,8] = 8,388,608
    float* h1   = ws;                                // [512,8,32,32] = 4,194,304
    float* h2   = h1 + (size_t)B * 8 * 32 * 32;      // [512,16,16,16]= 2,097,152
    float* h3   = uhat + (size_t)8388608;            // [512,32,8,8]  = 1,048,576
    float* v1   = h3 + (size_t)B * 32 * 8 * 8;       // [512,32,8]    =   131,072
    float* Wt   = v1 + (size_t)B * 256;              // [32,32,64,8]  =   524,288

    conv_relu_pool<3, 8, 64, 4><<<B, 256, 0, stream>>>(x, w1, b1, h1);
    conv_relu_pool<8, 16, 32, 4><<<B, 256, 0, stream>>>(h1, w2, b2, h2);
    conv_relu_pool<16, 32, 16, 2><<<B, 256, 0, stream>>>(h2, w3, b3, h3);
    transpose_w1<<<(32 * 32 * 64 * 2 + 255) / 256, 256, 0, stream>>>(rw1, Wt);
    {
        dim3 grid(B / 8, 8);   // K1: 512 blocks
        routing1_einsum<<<grid, 256, 0, stream>>>(h3, Wt, uhat);
    }
    routing1_iter<<<B, 256, 0, stream>>>(uhat, v1);
    routing2_fc<<<B, 256, 0, stream>>>(v1, rw2, fcw, fcb, out);
}